// Round 5
// baseline (79.796 us; speedup 1.0000x reference)
//
#include <hip/hip_runtime.h>
#include <hip/hip_bf16.h>

#define NROWS 8192
#define DDIM  512
#define NS    64
#define KK    8
#define HH    240
#define LDB   72      // bf16 staging pitch for BK=64 tiles (64 + 8 pad)
#define SP    136     // samp bf16 pitch (128 cols + pad)

typedef __attribute__((ext_vector_type(8))) short bf16x8;
typedef __attribute__((ext_vector_type(4))) float f32x4;
typedef __attribute__((ext_vector_type(2))) float f32x2;

// fp32 -> bf16 round-to-nearest-even
__device__ inline ushort f2bf(float x) {
    unsigned u = __float_as_uint(x);
    unsigned r = u + 0x7fffu + ((u >> 16) & 1u);
    return (ushort)(r >> 16);
}

// ---------------------------------------------------------------------------
// Kernel 0: pre-pack W1 to bf16 (frag-ready: [s][h][k] contiguous 8 bf16).
// ---------------------------------------------------------------------------
__global__ __launch_bounds__(256)
void pack_w1_kernel(const float* __restrict__ W1, ushort* __restrict__ W1b)
{
    int i = (blockIdx.x * 256 + threadIdx.x) * 4;   // 30720 threads * 4
    float4 v = *(const float4*)(W1 + i);
    ushort4 o;
    o.x = f2bf(v.x); o.y = f2bf(v.y); o.z = f2bf(v.z); o.w = f2bf(v.w);
    *(ushort4*)(W1b + i) = o;
}

// ---------------------------------------------------------------------------
// Main fused kernel:
//  phase 1: samp = bf16(rows) @ bf16(Th)^T, BK=64 staging, MFMA fp32 acc
//  phase 2: acc (+noise) -> bf16 samp in LDS [64 rows][128 (s,k) cols]
//  phase 3: layer-1 MFMA with A=W1 (rows=h), B=samp (cols=n); b1 in C-init
//           (float4), relu + packed-W3 fma, fused row-reductions:
//           X-blocks -> sumx[s][tile] ; Y-blocks -> maxy/sey[s][tile]
//  (b3 cancels exactly between mean_x and LSE_y -> omitted)
// grid = (256, 4): bx 0..127 X-tiles / 128..255 Y-tiles, by = 16-slice group.
// block = 256 (4 waves, 2x2 over 64 rows x 128 cols).
// ---------------------------------------------------------------------------
__global__ __launch_bounds__(256, 4)
void proj_mlp_kernel(const float* __restrict__ X,
                     const float* __restrict__ Y,
                     const float* __restrict__ Xn,
                     const float* __restrict__ Th,
                     const ushort* __restrict__ W1b,
                     const float* __restrict__ b1,
                     const float* __restrict__ W3,
                     const float* __restrict__ sig_p,
                     float* __restrict__ sumx,   // [NS][128]
                     float* __restrict__ maxy,   // [NS][128]
                     float* __restrict__ sey)    // [NS][128]
{
    __shared__ __align__(16) char smem[(64 + 128) * LDB * 2];   // 27648 B
    ushort* aT = (ushort*)smem;            // [64][LDB]
    ushort* bT = aT + 64 * LDB;            // [128][LDB]
    ushort* sl = (ushort*)smem;            // samp [64][SP] (phase-2/3 reuse)

    const int tid  = threadIdx.x;
    const int w    = __builtin_amdgcn_readfirstlane(tid >> 6);
    const int lane = tid & 63;
    const int bx   = blockIdx.x;
    const int by   = blockIdx.y;

    const bool isX = (bx < 128);
    const int  bxl = isX ? bx : (bx - 128);
    const float* srcA = (isX ? X : Y) + (size_t)bxl * 64 * DDIM;
    const float* srcB = Th + (size_t)by * 128 * DDIM;

    f32x4 acc[2][4];
#pragma unroll
    for (int m = 0; m < 2; ++m)
#pragma unroll
        for (int n = 0; n < 4; ++n) acc[m][n] = (f32x4){0.f, 0.f, 0.f, 0.f};

    const int wr  = (w >> 1) * 32;
    const int wc  = (w & 1) * 64;
    const int r16 = lane & 15;
    const int hi4 = lane >> 4;
    const int offA = (wr + r16) * LDB + hi4 * 8;
    const int offB = (wc + r16) * LDB + hi4 * 8;

    // staging regs: A 4 float4/thread (64x64), B 8 float4/thread (128x64)
    float4 ra[4], rb[8];
#pragma unroll
    for (int i = 0; i < 4; ++i) {
        int f = tid + i * 256;             // 0..1023: row f>>4, c4 f&15
        ra[i] = *(const float4*)(srcA + (size_t)(f >> 4) * DDIM + (f & 15) * 4);
    }
#pragma unroll
    for (int i = 0; i < 8; ++i) {
        int f = tid + i * 256;             // 0..2047
        rb[i] = *(const float4*)(srcB + (size_t)(f >> 4) * DDIM + (f & 15) * 4);
    }

#pragma unroll 1
    for (int kt = 0; kt < DDIM / 64; ++kt) {
        __syncthreads();
#pragma unroll
        for (int i = 0; i < 4; ++i) {
            int f = tid + i * 256;
            ushort4 o;
            o.x = f2bf(ra[i].x); o.y = f2bf(ra[i].y);
            o.z = f2bf(ra[i].z); o.w = f2bf(ra[i].w);
            *(ushort4*)(aT + (f >> 4) * LDB + (f & 15) * 4) = o;
        }
#pragma unroll
        for (int i = 0; i < 8; ++i) {
            int f = tid + i * 256;
            ushort4 o;
            o.x = f2bf(rb[i].x); o.y = f2bf(rb[i].y);
            o.z = f2bf(rb[i].z); o.w = f2bf(rb[i].w);
            *(ushort4*)(bT + (f >> 4) * LDB + (f & 15) * 4) = o;
        }
        __syncthreads();

        if (kt + 1 < DDIM / 64) {
            const int k0 = (kt + 1) * 64;
#pragma unroll
            for (int i = 0; i < 4; ++i) {
                int f = tid + i * 256;
                ra[i] = *(const float4*)(srcA + (size_t)(f >> 4) * DDIM + k0 + (f & 15) * 4);
            }
#pragma unroll
            for (int i = 0; i < 8; ++i) {
                int f = tid + i * 256;
                rb[i] = *(const float4*)(srcB + (size_t)(f >> 4) * DDIM + k0 + (f & 15) * 4);
            }
        }

#pragma unroll
        for (int ks = 0; ks < 2; ++ks) {
            bf16x8 af[2], bf[4];
#pragma unroll
            for (int m = 0; m < 2; ++m)
                af[m] = *(const bf16x8*)(aT + offA + m * 16 * LDB + ks * 32);
#pragma unroll
            for (int n = 0; n < 4; ++n)
                bf[n] = *(const bf16x8*)(bT + offB + n * 16 * LDB + ks * 32);
#pragma unroll
            for (int m = 0; m < 2; ++m)
#pragma unroll
                for (int n = 0; n < 4; ++n)
                    acc[m][n] = __builtin_amdgcn_mfma_f32_16x16x32_bf16(af[m], bf[n], acc[m][n], 0, 0, 0);
        }
    }

    // ---- phase 2: acc (+noise) -> bf16 samp LDS [row][col] ------------------
    const float sig = *sig_p;
    const bool addnoise = (sig > 0.f) && isX;
    const int n0g = bxl * 64;

    __syncthreads();   // staging LDS dead
#pragma unroll
    for (int m = 0; m < 2; ++m)
#pragma unroll
        for (int n = 0; n < 4; ++n) {
            int col = wc + n * 16 + r16;
#pragma unroll
            for (int j = 0; j < 4; ++j) {
                int row = wr + m * 16 + hi4 * 4 + j;
                float v = acc[m][n][j];
                if (addnoise)
                    v = fmaf(sig, Xn[(size_t)(n0g + row) * (NS * KK) + by * 128 + col], v);
                sl[row * SP + col] = f2bf(v);
            }
        }
    __syncthreads();

    // ---- phase 3: layer-1 MFMA (A=W1, B=samp), fused reductions -------------
#pragma unroll 1
    for (int si = 0; si < 4; ++si) {
        const int sloc = w * 4 + si;
        const int s    = by * 16 + sloc;

        // B-frags: samp rows nt*16+r16, k=0..7 live in lanes hi4==0
        bf16x8 bsamp[4];
#pragma unroll
        for (int nt = 0; nt < 4; ++nt) {
            bf16x8 t = {0, 0, 0, 0, 0, 0, 0, 0};
            if (hi4 == 0)
                t = *(const bf16x8*)(sl + (nt * 16 + r16) * SP + sloc * 8);
            bsamp[nt] = t;
        }

        const ushort* w1p = W1b + (size_t)s * HH * KK;
        const float*  b1p = b1 + s * HH;
        const float*  w3p = W3 + s * HH;

        f32x2 pn2[4];
#pragma unroll
        for (int nt = 0; nt < 4; ++nt) pn2[nt] = (f32x2){0.f, 0.f};

#pragma unroll 5
        for (int ht = 0; ht < HH / 16; ++ht) {
            bf16x8 aw = {0, 0, 0, 0, 0, 0, 0, 0};
            if (hi4 == 0)
                aw = *(const bf16x8*)(w1p + (ht * 16 + r16) * 8);
            float4 b4 = *(const float4*)(b1p + ht * 16 + hi4 * 4);
            float4 w4 = *(const float4*)(w3p + ht * 16 + hi4 * 4);
            f32x4 z = (f32x4){b4.x, b4.y, b4.z, b4.w};
            f32x2 w01 = (f32x2){w4.x, w4.y};
            f32x2 w23 = (f32x2){w4.z, w4.w};
            const f32x2 zero2 = (f32x2){0.f, 0.f};
#pragma unroll
            for (int nt = 0; nt < 4; ++nt) {
                f32x4 t = __builtin_amdgcn_mfma_f32_16x16x32_bf16(aw, bsamp[nt], z, 0, 0, 0);
                f32x2 t01 = (f32x2){t[0], t[1]};
                f32x2 t23 = (f32x2){t[2], t[3]};
                t01 = __builtin_elementwise_max(t01, zero2);
                t23 = __builtin_elementwise_max(t23, zero2);
                pn2[nt] = __builtin_elementwise_fma(t01, w01, pn2[nt]);
                pn2[nt] = __builtin_elementwise_fma(t23, w23, pn2[nt]);
            }
        }

        if (isX) {
            // total sum over 64 rows (rows spread over r16/nt, h-parts over hi4)
            float lsum = 0.f;
#pragma unroll
            for (int nt = 0; nt < 4; ++nt) lsum += pn2[nt].x + pn2[nt].y;
#pragma unroll
            for (int off = 1; off < 64; off <<= 1)
                lsum += __shfl_xor(lsum, off);
            if (lane == 0) sumx[s * 128 + bxl] = lsum;
        } else {
            // per-row preds: reduce h-parts across hi4 groups
            float p[4];
#pragma unroll
            for (int nt = 0; nt < 4; ++nt) {
                f32x2 v = pn2[nt];
                v.x += __shfl_xor(v.x, 16);
                v.y += __shfl_xor(v.y, 16);
                v.x += __shfl_xor(v.x, 32);
                v.y += __shfl_xor(v.y, 32);
                p[nt] = v.x + v.y;
            }
            float M = fmaxf(fmaxf(p[0], p[1]), fmaxf(p[2], p[3]));
            float se = __expf(p[0] - M) + __expf(p[1] - M)
                     + __expf(p[2] - M) + __expf(p[3] - M);
#pragma unroll
            for (int off = 1; off < 16; off <<= 1) {
                float Mo = __shfl_xor(M, off);
                float so = __shfl_xor(se, off);
                float Mm = fmaxf(M, Mo);
                se = se * __expf(M - Mm) + so * __expf(Mo - Mm);
                M = Mm;
            }
            if (lane == 0) {
                maxy[s * 128 + bxl] = M;
                sey[s * 128 + bxl]  = se;
            }
        }
    }
}

// ---------------------------------------------------------------------------
// Final: combine 128 partials per slice, term_s = LSE - logN - mean, then
// mean over slices -> scalar. (b3 cancels; pred values are sans-b3.)
// ---------------------------------------------------------------------------
__global__ __launch_bounds__(64)
void final_kernel(const float* __restrict__ sumx,
                  const float* __restrict__ maxy,
                  const float* __restrict__ sey,
                  float* __restrict__ out)
{
    const int s = threadIdx.x;
    const float* sxp = sumx + s * 128;
    const float* myp = maxy + s * 128;
    const float* sep = sey + s * 128;

    float sum = 0.f, M = -3.4e38f;
#pragma unroll 8
    for (int i = 0; i < 128; ++i) {
        sum += sxp[i];
        M = fmaxf(M, myp[i]);
    }
    float se = 0.f;
#pragma unroll 8
    for (int i = 0; i < 128; ++i)
        se += sep[i] * __expf(myp[i] - M);

    float lse  = M + logf(se);
    float term = lse - logf((float)NROWS) - sum * (1.0f / (float)NROWS);
#pragma unroll
    for (int off = 1; off < 64; off <<= 1) term += __shfl_xor(term, off);
    if (s == 0) out[0] = term * (1.0f / (float)NS);
}

// ---------------------------------------------------------------------------
extern "C" void kernel_launch(void* const* d_in, const int* in_sizes, int n_in,
                              void* d_out, int out_size, void* d_ws, size_t ws_size,
                              hipStream_t stream)
{
    const float* X   = (const float*)d_in[0];
    const float* Y   = (const float*)d_in[1];
    const float* Xn  = (const float*)d_in[2];
    const float* Th  = (const float*)d_in[3];
    const float* W1  = (const float*)d_in[4];
    const float* b1  = (const float*)d_in[5];
    const float* W3  = (const float*)d_in[6];
    // d_in[7] = b3 (cancels exactly between mean_x and LSE_y -> unused)
    const float* sig = (const float*)d_in[8];

    ushort* W1b  = (ushort*)d_ws;                              // 245760 B
    float*  sumx = (float*)((char*)d_ws + (size_t)NS * HH * KK * 2);
    float*  maxy = sumx + NS * 128;
    float*  sey  = maxy + NS * 128;

    pack_w1_kernel<<<NS * HH * KK / 1024, 256, 0, stream>>>(W1, W1b);

    dim3 g1(256, 4, 1);
    proj_mlp_kernel<<<g1, 256, 0, stream>>>(X, Y, Xn, Th, W1b, b1, W3,
                                            sig, sumx, maxy, sey);
    final_kernel<<<1, 64, 0, stream>>>(sumx, maxy, sey, (float*)d_out);
}